// Round 5
// baseline (420.999 us; speedup 1.0000x reference)
//
#include <hip/hip_runtime.h>

#define BS 2048
#define EMB 1024
#define NHEAD 8
#define HDIM 128

typedef unsigned short u16;
typedef __attribute__((ext_vector_type(8))) short bf16x8;
typedef __attribute__((ext_vector_type(4))) float f32x4;

__device__ __forceinline__ u16 f32_bf16(float f) {
  unsigned u = __float_as_uint(f);
  u += 0x7fffu + ((u >> 16) & 1u);
  return (u16)(u >> 16);
}
__device__ __forceinline__ float bf2f(u16 x) {
  return __uint_as_float((unsigned)x << 16);
}

__device__ __forceinline__ void gld_lds16(const void* g, void* l) {
  __builtin_amdgcn_global_load_lds(
      (const __attribute__((address_space(1))) void*)g,
      (__attribute__((address_space(3))) void*)l, 16, 0, 0);
}

// ---------------- GEMM core: C = A @ B^T (+bias), 128x128 tile, BK=32 ----------
// AF32/BF32: operand is fp32 in global, converted to bf16 during LDS staging.
// mode: 0 = fp32 out, 1 = bf16 out, 2 = bf16 transposed store (Ct[n][m])
template <int AF32, int BF32>
__device__ __forceinline__ void gemm_core(
    const void* __restrict__ Ap, const void* __restrict__ Bp, void* __restrict__ Cp,
    const float* __restrict__ bias, int K, int lda, int ldb, int ldc,
    long cbase, int mode, int relu, int m0, int n0) {
  __shared__ __align__(16) u16 As[128 * 32];
  __shared__ __align__(16) u16 Bs[128 * 32];
  const int t = threadIdx.x;
  const int lane = t & 63, l15 = lane & 15, quad = lane >> 4;
  const int wv = t >> 6, wr = wv & 1, wc = wv >> 1;
  const int wbase = t & ~63;

  f32x4 acc[4][4];
#pragma unroll
  for (int r = 0; r < 4; ++r)
#pragma unroll
    for (int c = 0; c < 4; ++c) acc[r][c] = (f32x4){0.f, 0.f, 0.f, 0.f};

  for (int k0 = 0; k0 < K; k0 += 32) {
#pragma unroll
    for (int i = 0; i < 2; ++i) {
      int s = i * 256 + t;
      int row = s >> 2, kc = (s & 3) * 8;
      if constexpr (AF32) {
        const float* src = (const float*)Ap + (long)(m0 + row) * lda + k0 + kc;
        float4 v0 = *(const float4*)src;
        float4 v1 = *(const float4*)(src + 4);
        uint4 w;
        w.x = (unsigned)f32_bf16(v0.x) | ((unsigned)f32_bf16(v0.y) << 16);
        w.y = (unsigned)f32_bf16(v0.z) | ((unsigned)f32_bf16(v0.w) << 16);
        w.z = (unsigned)f32_bf16(v1.x) | ((unsigned)f32_bf16(v1.y) << 16);
        w.w = (unsigned)f32_bf16(v1.z) | ((unsigned)f32_bf16(v1.w) << 16);
        *(uint4*)&As[row * 32 + kc] = w;
      } else {
        gld_lds16((const u16*)Ap + (long)(m0 + row) * lda + k0 + kc,
                  As + (i * 256 + wbase) * 8);
      }
    }
#pragma unroll
    for (int i = 0; i < 2; ++i) {
      int s = i * 256 + t;
      int row = s >> 2, kc = (s & 3) * 8;
      if constexpr (BF32) {
        const float* src = (const float*)Bp + (long)(n0 + row) * ldb + k0 + kc;
        float4 v0 = *(const float4*)src;
        float4 v1 = *(const float4*)(src + 4);
        uint4 w;
        w.x = (unsigned)f32_bf16(v0.x) | ((unsigned)f32_bf16(v0.y) << 16);
        w.y = (unsigned)f32_bf16(v0.z) | ((unsigned)f32_bf16(v0.w) << 16);
        w.z = (unsigned)f32_bf16(v1.x) | ((unsigned)f32_bf16(v1.y) << 16);
        w.w = (unsigned)f32_bf16(v1.z) | ((unsigned)f32_bf16(v1.w) << 16);
        *(uint4*)&Bs[row * 32 + kc] = w;
      } else {
        gld_lds16((const u16*)Bp + (long)(n0 + row) * ldb + k0 + kc,
                  Bs + (i * 256 + wbase) * 8);
      }
    }
    __syncthreads();
    bf16x8 fa[4], fb[4];
#pragma unroll
    for (int r = 0; r < 4; ++r)
      fa[r] = *(const bf16x8*)&As[(wr * 64 + r * 16 + l15) * 32 + quad * 8];
#pragma unroll
    for (int c = 0; c < 4; ++c)
      fb[c] = *(const bf16x8*)&Bs[(wc * 64 + c * 16 + l15) * 32 + quad * 8];
#pragma unroll
    for (int r = 0; r < 4; ++r)
#pragma unroll
      for (int c = 0; c < 4; ++c)
        acc[r][c] = __builtin_amdgcn_mfma_f32_16x16x32_bf16(fa[r], fb[c], acc[r][c], 0, 0, 0);
    __syncthreads();
  }

#pragma unroll
  for (int r = 0; r < 4; ++r)
#pragma unroll
    for (int c = 0; c < 4; ++c) {
      const int m = m0 + wr * 64 + r * 16 + quad * 4;
      const int n = n0 + wc * 64 + c * 16 + l15;
      const float bv = bias ? bias[n] : 0.f;
      f32x4 v = acc[r][c];
      if (mode == 2) {
        ushort4 o;
        o.x = f32_bf16(v[0] + bv);
        o.y = f32_bf16(v[1] + bv);
        o.z = f32_bf16(v[2] + bv);
        o.w = f32_bf16(v[3] + bv);
        *(ushort4*)((u16*)Cp + cbase + (long)n * ldc + m) = o;
      } else {
#pragma unroll
        for (int i = 0; i < 4; ++i) {
          float x = v[i] + bv;
          if (relu) x = fmaxf(x, 0.f);
          if (mode == 0)
            ((float*)Cp)[cbase + (long)(m + i) * ldc + n] = x;
          else
            ((u16*)Cp)[cbase + (long)(m + i) * ldc + n] = f32_bf16(x);
        }
      }
    }
}

// generic z-batched GEMM (linear z offsets, in elements of the operand dtype)
template <int AF32, int BF32>
__global__ __launch_bounds__(256) void gemm_bt_k(
    const void* __restrict__ A, const void* __restrict__ B, void* __restrict__ C,
    const float* __restrict__ bias, int K, int lda, int ldb, int ldc,
    long aOffZ, long bOffZ, long cOffZ, int mode, int relu) {
  const void* Az = AF32 ? (const void*)((const float*)A + (long)blockIdx.z * aOffZ)
                        : (const void*)((const u16*)A + (long)blockIdx.z * aOffZ);
  const void* Bz = BF32 ? (const void*)((const float*)B + (long)blockIdx.z * bOffZ)
                        : (const void*)((const u16*)B + (long)blockIdx.z * bOffZ);
  gemm_core<AF32, BF32>(Az, Bz, C, bias, K, lda, ldb, ldc,
                        (long)blockIdx.z * cOffZ, mode, relu,
                        blockIdx.y * 128, blockIdx.x * 128);
}

// Q/K/V projections in one launch, fp32 inputs: z=0 Q(x1), z=1 K(x2), z=2 V(x2, transposed)
__global__ __launch_bounds__(256) void qkv_kernel(
    const float* __restrict__ x1, const float* __restrict__ x2,
    const float* __restrict__ Wq, const float* __restrict__ Wk, const float* __restrict__ Wv,
    const float* __restrict__ bq, const float* __restrict__ bk, const float* __restrict__ bv,
    u16* __restrict__ Qb, u16* __restrict__ Kb, u16* __restrict__ Vt) {
  const int z = blockIdx.z;
  const float* A = (z == 0) ? x1 : x2;
  const float* B = (z == 0) ? Wq : (z == 1) ? Wk : Wv;
  void* C = (z == 0) ? (void*)Qb : (z == 1) ? (void*)Kb : (void*)Vt;
  const float* bias = (z == 0) ? bq : (z == 1) ? bk : bv;
  const int mode = (z == 2) ? 2 : 1;
  const int ldc = (z == 2) ? 2048 : 1024;
  gemm_core<1, 1>(A, B, C, bias, 1024, 1024, 1024, ldc, 0, mode, 0,
                  blockIdx.y * 128, blockIdx.x * 128);
}

// PV split-K: z = h*2 + ks; partials[ks][n][h*128+d] bf16
__global__ __launch_bounds__(256) void pv_kernel(
    const u16* __restrict__ P, const u16* __restrict__ Vt, u16* __restrict__ parts) {
  const int h = blockIdx.z >> 1, ks = blockIdx.z & 1;
  const u16* A = P + (long)h * BS * BS + ks * 1024;
  const u16* B = Vt + (long)h * HDIM * 2048 + ks * 1024;
  const long cbase = (long)ks * BS * 1024 + h * HDIM;
  gemm_core<0, 0>(A, B, parts, nullptr, 1024, 2048, 2048, 1024, cbase, 1, 0,
                  blockIdx.y * 128, 0);
}

// attnb = bf16(p0 + p1)
__global__ __launch_bounds__(256) void reduce2_bf16(
    const u16* __restrict__ p0, const u16* __restrict__ p1, u16* __restrict__ out) {
  int i = blockIdx.x * 256 + threadIdx.x;  // ushort4 index, 524288 total
  ushort4 a = ((const ushort4*)p0)[i];
  ushort4 b = ((const ushort4*)p1)[i];
  ushort4 o;
  o.x = f32_bf16(bf2f(a.x) + bf2f(b.x));
  o.y = f32_bf16(bf2f(a.y) + bf2f(b.y));
  o.z = f32_bf16(bf2f(a.z) + bf2f(b.z));
  o.w = f32_bf16(bf2f(a.w) + bf2f(b.w));
  ((ushort4*)out)[i] = o;
}

// ------------- scores + softmax-over-heads, P[h][n][m] bf16 out -------------
// v3: double-buffered Q+K staging (1 barrier/head), direct register->global P store.
__global__ __launch_bounds__(256) void scores_softmax(
    const u16* __restrict__ Q, const u16* __restrict__ Km, u16* __restrict__ P) {
  __shared__ __align__(16) u16 Qs[2][4096];
  __shared__ __align__(16) u16 Ks[2][16384];
  const int t = threadIdx.x;
  const int lane = t & 63, l15 = lane & 15, quad = lane >> 4;
  const int wv = t >> 6, wbase = t & ~63;
  const int n0 = blockIdx.y * 32, m0 = blockIdx.x * 128;

  auto stage = [&](int h, int b) {
#pragma unroll
    for (int i = 0; i < 2; ++i) {
      int s = i * 256 + t;
      gld_lds16(Q + (long)(n0 + ((s >> 2) & 31)) * EMB + h * HDIM + (s >> 7) * 32 + (s & 3) * 8,
                &Qs[b][(i * 256 + wbase) * 8]);
    }
#pragma unroll
    for (int i = 0; i < 8; ++i) {
      int s = i * 256 + t;
      gld_lds16(Km + (long)(m0 + ((s >> 2) & 127)) * EMB + h * HDIM + (s >> 9) * 32 + (s & 3) * 8,
                &Ks[b][(i * 256 + wbase) * 8]);
    }
  };

  f32x4 acc[8][2][2];
#pragma unroll
  for (int h = 0; h < 8; ++h)
#pragma unroll
    for (int r = 0; r < 2; ++r)
#pragma unroll
      for (int c = 0; c < 2; ++c) acc[h][r][c] = (f32x4){0.f, 0.f, 0.f, 0.f};

  stage(0, 0);
#pragma unroll
  for (int h = 0; h < 8; ++h) {
    __syncthreads();  // buf[h&1] staged; buf[(h+1)&1] ds_reads (h-1) drained
    if (h < 7) stage(h + 1, (h + 1) & 1);
    const u16* qb = Qs[h & 1];
    const u16* kb = Ks[h & 1];
#pragma unroll
    for (int kk = 0; kk < 4; ++kk) {
      bf16x8 fa[2], fb[2];
#pragma unroll
      for (int r = 0; r < 2; ++r)
        fa[r] = *(const bf16x8*)&qb[kk * 1024 + (r * 16 + l15) * 32 + quad * 8];
#pragma unroll
      for (int c = 0; c < 2; ++c)
        fb[c] = *(const bf16x8*)&kb[kk * 4096 + (wv * 32 + c * 16 + l15) * 32 + quad * 8];
#pragma unroll
      for (int r = 0; r < 2; ++r)
#pragma unroll
        for (int c = 0; c < 2; ++c)
          acc[h][r][c] = __builtin_amdgcn_mfma_f32_16x16x32_bf16(fa[r], fb[c], acc[h][r][c], 0, 0, 0);
    }
  }

  // softmax over heads: purely per-lane (lane holds same (n,m) for all h)
  const float scale = 0.08838834764831845f;  // 1/sqrt(128)
#pragma unroll
  for (int r = 0; r < 2; ++r)
#pragma unroll
    for (int c = 0; c < 2; ++c)
#pragma unroll
      for (int i = 0; i < 4; ++i) {
        float mx = acc[0][r][c][i];
#pragma unroll
        for (int h = 1; h < 8; ++h) mx = fmaxf(mx, acc[h][r][c][i]);
        float sum = 0.f;
#pragma unroll
        for (int h = 0; h < 8; ++h) {
          float e = __expf((acc[h][r][c][i] - mx) * scale);
          acc[h][r][c][i] = e;
          sum += e;
        }
        float inv = 1.f / sum;
#pragma unroll
        for (int h = 0; h < 8; ++h) acc[h][r][c][i] *= inv;
      }

  // direct register -> global stores: m = l15 (lane-contiguous, 32B segments)
#pragma unroll
  for (int h = 0; h < 8; ++h) {
    u16* ph = P + (long)h * BS * BS;
#pragma unroll
    for (int r = 0; r < 2; ++r)
#pragma unroll
      for (int c = 0; c < 2; ++c)
#pragma unroll
        for (int i = 0; i < 4; ++i)
          ph[(long)(n0 + r * 16 + quad * 4 + i) * BS + m0 + wv * 32 + c * 16 + l15] =
              f32_bf16(acc[h][r][c][i]);
  }
}

// ------- 3-way residual + column-bias + layernorm; fp32 out (+ optional bf16) -------
__global__ __launch_bounds__(256) void ln_residual3(
    const float* __restrict__ x, const float* __restrict__ y0, const float* __restrict__ y1,
    const float* __restrict__ colb, const float* __restrict__ g, const float* __restrict__ b,
    float* __restrict__ out32, u16* __restrict__ out16) {
  const int row = blockIdx.x, t = threadIdx.x;
  float4 v = ((const float4*)(x + (long)row * EMB))[t];
  float4 u0 = ((const float4*)(y0 + (long)row * EMB))[t];
  float4 u1 = ((const float4*)(y1 + (long)row * EMB))[t];
  float4 cb = ((const float4*)colb)[t];
  v.x += u0.x + u1.x + cb.x;
  v.y += u0.y + u1.y + cb.y;
  v.z += u0.z + u1.z + cb.z;
  v.w += u0.w + u1.w + cb.w;
  float s = v.x + v.y + v.z + v.w;
  float q = v.x * v.x + v.y * v.y + v.z * v.z + v.w * v.w;
#pragma unroll
  for (int off = 32; off > 0; off >>= 1) {
    s += __shfl_xor(s, off);
    q += __shfl_xor(q, off);
  }
  __shared__ float red[8];
  const int wv = t >> 6, lane = t & 63;
  if (lane == 0) { red[wv] = s; red[4 + wv] = q; }
  __syncthreads();
  s = red[0] + red[1] + red[2] + red[3];
  q = red[4] + red[5] + red[6] + red[7];
  const float mean = s * (1.f / EMB);
  const float var = q * (1.f / EMB) - mean * mean;
  const float rstd = rsqrtf(var + 1e-5f);
  float4 gg = ((const float4*)g)[t];
  float4 bb = ((const float4*)b)[t];
  float4 o;
  o.x = (v.x - mean) * rstd * gg.x + bb.x;
  o.y = (v.y - mean) * rstd * gg.y + bb.y;
  o.z = (v.z - mean) * rstd * gg.z + bb.z;
  o.w = (v.w - mean) * rstd * gg.w + bb.w;
  ((float4*)(out32 + (long)row * EMB))[t] = o;
  if (out16) {
    ushort4 ho;
    ho.x = f32_bf16(o.x); ho.y = f32_bf16(o.y); ho.z = f32_bf16(o.z); ho.w = f32_bf16(o.w);
    ((ushort4*)(out16 + (long)row * EMB))[t] = ho;
  }
}

extern "C" void kernel_launch(void* const* d_in, const int* in_sizes, int n_in,
                              void* d_out, int out_size, void* d_ws, size_t ws_size,
                              hipStream_t stream) {
  const float* x1 = (const float*)d_in[0];
  const float* x2 = (const float*)d_in[1];
  const float* Wq = (const float*)d_in[2];
  const float* bq = (const float*)d_in[3];
  const float* Wk = (const float*)d_in[4];
  const float* bk = (const float*)d_in[5];
  const float* Wv = (const float*)d_in[6];
  const float* bv = (const float*)d_in[7];
  const float* Wo = (const float*)d_in[8];
  const float* bo = (const float*)d_in[9];
  const float* W1 = (const float*)d_in[10];
  const float* b1 = (const float*)d_in[11];
  const float* W2 = (const float*)d_in[12];
  const float* b2 = (const float*)d_in[13];
  const float* g1 = (const float*)d_in[14];
  const float* be1 = (const float*)d_in[15];
  const float* g2 = (const float*)d_in[16];
  const float* be2 = (const float*)d_in[17];

  char* ws = (char*)d_ws;
  const size_t MB = 1ull << 20;
  u16* Qb  = (u16*)(ws + 0 * MB);    // 4 MB (dead after scores; pv partial 0)
  u16* Kb  = (u16*)(ws + 4 * MB);    // 4 MB (dead after scores; pv partial 1)
  u16* Vtb = (u16*)(ws + 8 * MB);    // 4 MB (transposed V: [h*128+d][m], ld 2048)
  u16* attnb = (u16*)(ws + 12 * MB); // 4 MB
  u16* P   = (u16*)(ws + 16 * MB);   // 64 MB (dead after pv_kernel)
  u16* pvParts = Qb;                 // 2 contiguous 4 MB partials @ 0
  // post-attention region aliases P:
  float* woP0 = (float*)(ws + 16 * MB);  // 8 MB
  float* woP1 = (float*)(ws + 24 * MB);  // 8 MB
  float* h32  = (float*)(ws + 32 * MB);  // 8 MB
  u16*  h16   = (u16*)(ws + 40 * MB);    // 4 MB
  u16*  ffn1b = (u16*)(ws + 44 * MB);    // 16 MB -> 60 MB peak
  float* f2P0 = woP0;                    // ffn2 partials alias wo partials
  float* f2P1 = woP1;

  // 1. Q/K/V projections straight from fp32 inputs (one launch, 384 blocks)
  qkv_kernel<<<dim3(8, 16, 3), 256, 0, stream>>>(x1, x2, Wq, Wk, Wv, bq, bk, bv, Qb, Kb, Vtb);

  // 2. scores + softmax over heads -> P[h][n][m]
  scores_softmax<<<dim3(16, 64), 256, 0, stream>>>(Qb, Kb, P);

  // 3. PV split-K (256 blocks), bf16 partials (overwrite Qb/Kb)
  pv_kernel<<<dim3(1, 16, 16), 256, 0, stream>>>(P, Vtb, pvParts);

  // 4. attnb = p0 + p1
  reduce2_bf16<<<2048, 256, 0, stream>>>(pvParts, pvParts + (long)BS * EMB, attnb);

  // 5. Wo GEMM split-K x2, fp32 partials (bias folded into LN); B = Wo fp32
  gemm_bt_k<0, 1><<<dim3(8, 16, 2), 256, 0, stream>>>(attnb, Wo, woP0, nullptr,
                                                      512, 1024, 1024, 1024,
                                                      512, 512, (long)BS * 1024, 0, 0);

  // 6. h = LN(x1 + woP0 + woP1 + bo)
  ln_residual3<<<2048, 256, 0, stream>>>(x1, woP0, woP1, bo, g1, be1, h32, h16);

  // 7. FFN1 (+bias+relu), 512 blocks; B = W1 fp32
  gemm_bt_k<0, 1><<<dim3(32, 16, 1), 256, 0, stream>>>(h16, W1, ffn1b, b1,
                                                       1024, 1024, 1024, 4096,
                                                       0, 0, 0, 1, 1);

  // 8. FFN2 split-K x2, fp32 partials (bias folded into LN); B = W2 fp32
  gemm_bt_k<0, 1><<<dim3(8, 16, 2), 256, 0, stream>>>(ffn1b, W2, f2P0, nullptr,
                                                      2048, 4096, 4096, 1024,
                                                      2048, 2048, (long)BS * 1024, 0, 0);

  // 9. out = LN(h + f2P0 + f2P1 + b2)
  ln_residual3<<<2048, 256, 0, stream>>>(h32, f2P0, f2P1, b2, g2, be2, (float*)d_out, nullptr);
}

// Round 6
// 339.245 us; speedup vs baseline: 1.2410x; 1.2410x over previous
//
#include <hip/hip_runtime.h>

#define BS 2048
#define EMB 1024
#define NHEAD 8
#define HDIM 128

typedef unsigned short u16;
typedef __attribute__((ext_vector_type(8))) short bf16x8;
typedef __attribute__((ext_vector_type(4))) float f32x4;

__device__ __forceinline__ u16 f32_bf16(float f) {
  unsigned u = __float_as_uint(f);
  u += 0x7fffu + ((u >> 16) & 1u);
  return (u16)(u >> 16);
}
__device__ __forceinline__ float bf2f(u16 x) {
  return __uint_as_float((unsigned)x << 16);
}

__device__ __forceinline__ void gld_lds16(const void* g, void* l) {
  __builtin_amdgcn_global_load_lds(
      (const __attribute__((address_space(1))) void*)g,
      (__attribute__((address_space(3))) void*)l, 16, 0, 0);
}

// ---------------- fp32 -> bf16: ALL weights/activations in ONE kernel ----------
// segs of 256K v4 (1M elems): [0,2)=x1 [2,4)=x2 [4]=Wq [5]=Wk [6]=Wv [7]=Wo
// [8,12)=W1 [12,16)=W2
struct CvtArgs { const float* src[8]; };
__global__ __launch_bounds__(256) void cvt_all(CvtArgs a, u16* __restrict__ dst) {
  long i = (long)blockIdx.x * 256 + threadIdx.x;  // v4 index
  int seg = (int)(i >> 18);
  const float* src; long b;
  if (seg < 2)       { src = a.src[0]; b = 0; }
  else if (seg < 4)  { src = a.src[1]; b = 2L << 18; }
  else if (seg == 4) { src = a.src[2]; b = 4L << 18; }
  else if (seg == 5) { src = a.src[3]; b = 5L << 18; }
  else if (seg == 6) { src = a.src[4]; b = 6L << 18; }
  else if (seg == 7) { src = a.src[5]; b = 7L << 18; }
  else if (seg < 12) { src = a.src[6]; b = 8L << 18; }
  else               { src = a.src[7]; b = 12L << 18; }
  float4 v = ((const float4*)src)[i - b];
  ushort4 o;
  o.x = f32_bf16(v.x); o.y = f32_bf16(v.y); o.z = f32_bf16(v.z); o.w = f32_bf16(v.w);
  ((ushort4*)dst)[i] = o;
}

// ---------------- GEMM core: C = A @ B^T (+bias), 128x128 tile, BK=32 ----------
// mode: 0 = fp32 out, 1 = bf16 out, 2 = bf16 transposed store (Ct[n][m])
__device__ __forceinline__ void gemm_core(
    const u16* __restrict__ A, const u16* __restrict__ B, void* __restrict__ Cp,
    const float* __restrict__ bias, int K, int lda, int ldb, int ldc,
    long cbase, int mode, int relu, int m0, int n0) {
  __shared__ __align__(16) u16 As[128 * 32];
  __shared__ __align__(16) u16 Bs[128 * 32];
  const int t = threadIdx.x;
  const int lane = t & 63, l15 = lane & 15, quad = lane >> 4;
  const int wv = t >> 6, wr = wv & 1, wc = wv >> 1;
  const int wbase = t & ~63;

  f32x4 acc[4][4];
#pragma unroll
  for (int r = 0; r < 4; ++r)
#pragma unroll
    for (int c = 0; c < 4; ++c) acc[r][c] = (f32x4){0.f, 0.f, 0.f, 0.f};

  for (int k0 = 0; k0 < K; k0 += 32) {
#pragma unroll
    for (int i = 0; i < 2; ++i) {
      int s = i * 256 + t;
      gld_lds16(A + (long)(m0 + (s >> 2)) * lda + k0 + (s & 3) * 8,
                As + (i * 256 + wbase) * 8);
    }
#pragma unroll
    for (int i = 0; i < 2; ++i) {
      int s = i * 256 + t;
      gld_lds16(B + (long)(n0 + (s >> 2)) * ldb + k0 + (s & 3) * 8,
                Bs + (i * 256 + wbase) * 8);
    }
    __syncthreads();
    bf16x8 fa[4], fb[4];
#pragma unroll
    for (int r = 0; r < 4; ++r)
      fa[r] = *(const bf16x8*)&As[(wr * 64 + r * 16 + l15) * 32 + quad * 8];
#pragma unroll
    for (int c = 0; c < 4; ++c)
      fb[c] = *(const bf16x8*)&Bs[(wc * 64 + c * 16 + l15) * 32 + quad * 8];
#pragma unroll
    for (int r = 0; r < 4; ++r)
#pragma unroll
      for (int c = 0; c < 4; ++c)
        acc[r][c] = __builtin_amdgcn_mfma_f32_16x16x32_bf16(fa[r], fb[c], acc[r][c], 0, 0, 0);
    __syncthreads();
  }

#pragma unroll
  for (int r = 0; r < 4; ++r)
#pragma unroll
    for (int c = 0; c < 4; ++c) {
      const int m = m0 + wr * 64 + r * 16 + quad * 4;
      const int n = n0 + wc * 64 + c * 16 + l15;
      const float bv = bias ? bias[n] : 0.f;
      f32x4 v = acc[r][c];
      if (mode == 2) {
        ushort4 o;
        o.x = f32_bf16(v[0] + bv);
        o.y = f32_bf16(v[1] + bv);
        o.z = f32_bf16(v[2] + bv);
        o.w = f32_bf16(v[3] + bv);
        *(ushort4*)((u16*)Cp + cbase + (long)n * ldc + m) = o;
      } else {
#pragma unroll
        for (int i = 0; i < 4; ++i) {
          float x = v[i] + bv;
          if (relu) x = fmaxf(x, 0.f);
          if (mode == 0)
            ((float*)Cp)[cbase + (long)(m + i) * ldc + n] = x;
          else
            ((u16*)Cp)[cbase + (long)(m + i) * ldc + n] = f32_bf16(x);
        }
      }
    }
}

// generic z-batched GEMM (linear z offsets in elements)
__global__ __launch_bounds__(256) void gemm_bt_k(
    const u16* __restrict__ A, const u16* __restrict__ B, void* __restrict__ C,
    const float* __restrict__ bias, int K, int lda, int ldb, int ldc,
    long aOffZ, long bOffZ, long cOffZ, int mode, int relu) {
  gemm_core(A + (long)blockIdx.z * aOffZ, B + (long)blockIdx.z * bOffZ, C, bias,
            K, lda, ldb, ldc, (long)blockIdx.z * cOffZ, mode, relu,
            blockIdx.y * 128, blockIdx.x * 128);
}

// Q/K/V projections in one launch: z=0 Q(x1), z=1 K(x2), z=2 V(x2, transposed out)
__global__ __launch_bounds__(256) void qkv_kernel(
    const u16* __restrict__ x1b, const u16* __restrict__ x2b,
    const u16* __restrict__ Wqb, const u16* __restrict__ Wkb, const u16* __restrict__ Wvb,
    const float* __restrict__ bq, const float* __restrict__ bk, const float* __restrict__ bv,
    u16* __restrict__ Qb, u16* __restrict__ Kb, u16* __restrict__ Vt) {
  const int z = blockIdx.z;
  const u16* A = (z == 0) ? x1b : x2b;
  const u16* B = (z == 0) ? Wqb : (z == 1) ? Wkb : Wvb;
  void* C = (z == 0) ? (void*)Qb : (z == 1) ? (void*)Kb : (void*)Vt;
  const float* bias = (z == 0) ? bq : (z == 1) ? bk : bv;
  const int mode = (z == 2) ? 2 : 1;
  const int ldc = (z == 2) ? 2048 : 1024;
  gemm_core(A, B, C, bias, 1024, 1024, 1024, ldc, 0, mode, 0,
            blockIdx.y * 128, blockIdx.x * 128);
}

// PV split-K x4: z = h*4 + ks; partials[ks][n][h*128+d] bf16
__global__ __launch_bounds__(256) void pv_kernel(
    const u16* __restrict__ P, const u16* __restrict__ Vt,
    u16* p0, u16* p1, u16* p2, u16* p3) {
  const int h = blockIdx.z >> 2, ks = blockIdx.z & 3;
  u16* parts = (ks == 0) ? p0 : (ks == 1) ? p1 : (ks == 2) ? p2 : p3;
  const u16* A = P + (long)h * BS * BS + ks * 512;
  const u16* B = Vt + (long)h * HDIM * 2048 + ks * 512;
  gemm_core(A, B, parts, nullptr, 512, 2048, 2048, 1024, (long)h * HDIM, 1, 0,
            blockIdx.y * 128, 0);
}

// out = bf16(p0+p1+p2+p3)
__global__ __launch_bounds__(256) void reduce4p_bf16(
    const u16* __restrict__ p0, const u16* __restrict__ p1,
    const u16* __restrict__ p2, const u16* __restrict__ p3, u16* __restrict__ out) {
  long i = (long)blockIdx.x * 256 + threadIdx.x;  // ushort4 idx, 524288 total
  ushort4 a = ((const ushort4*)p0)[i];
  ushort4 b = ((const ushort4*)p1)[i];
  ushort4 c = ((const ushort4*)p2)[i];
  ushort4 d = ((const ushort4*)p3)[i];
  ushort4 o;
  o.x = f32_bf16(bf2f(a.x) + bf2f(b.x) + bf2f(c.x) + bf2f(d.x));
  o.y = f32_bf16(bf2f(a.y) + bf2f(b.y) + bf2f(c.y) + bf2f(d.y));
  o.z = f32_bf16(bf2f(a.z) + bf2f(b.z) + bf2f(c.z) + bf2f(d.z));
  o.w = f32_bf16(bf2f(a.w) + bf2f(b.w) + bf2f(c.w) + bf2f(d.w));
  ((ushort4*)out)[i] = o;
}

// ------------- scores + softmax-over-heads, P[h][n][m] bf16 out -------------
// v3: double-buffered Q+K staging (1 barrier/head), direct register->global P store.
__global__ __launch_bounds__(256) void scores_softmax(
    const u16* __restrict__ Q, const u16* __restrict__ Km, u16* __restrict__ P) {
  __shared__ __align__(16) u16 Qs[2][4096];
  __shared__ __align__(16) u16 Ks[2][16384];
  const int t = threadIdx.x;
  const int lane = t & 63, l15 = lane & 15, quad = lane >> 4;
  const int wv = t >> 6, wbase = t & ~63;
  const int n0 = blockIdx.y * 32, m0 = blockIdx.x * 128;

  auto stage = [&](int h, int b) {
#pragma unroll
    for (int i = 0; i < 2; ++i) {
      int s = i * 256 + t;
      gld_lds16(Q + (long)(n0 + ((s >> 2) & 31)) * EMB + h * HDIM + (s >> 7) * 32 + (s & 3) * 8,
                &Qs[b][(i * 256 + wbase) * 8]);
    }
#pragma unroll
    for (int i = 0; i < 8; ++i) {
      int s = i * 256 + t;
      gld_lds16(Km + (long)(m0 + ((s >> 2) & 127)) * EMB + h * HDIM + (s >> 9) * 32 + (s & 3) * 8,
                &Ks[b][(i * 256 + wbase) * 8]);
    }
  };

  f32x4 acc[8][2][2];
#pragma unroll
  for (int h = 0; h < 8; ++h)
#pragma unroll
    for (int r = 0; r < 2; ++r)
#pragma unroll
      for (int c = 0; c < 2; ++c) acc[h][r][c] = (f32x4){0.f, 0.f, 0.f, 0.f};

  stage(0, 0);
#pragma unroll
  for (int h = 0; h < 8; ++h) {
    __syncthreads();  // buf[h&1] staged; buf[(h+1)&1] ds_reads (h-1) drained
    if (h < 7) stage(h + 1, (h + 1) & 1);
    const u16* qb = Qs[h & 1];
    const u16* kb = Ks[h & 1];
#pragma unroll
    for (int kk = 0; kk < 4; ++kk) {
      bf16x8 fa[2], fb[2];
#pragma unroll
      for (int r = 0; r < 2; ++r)
        fa[r] = *(const bf16x8*)&qb[kk * 1024 + (r * 16 + l15) * 32 + quad * 8];
#pragma unroll
      for (int c = 0; c < 2; ++c)
        fb[c] = *(const bf16x8*)&kb[kk * 4096 + (wv * 32 + c * 16 + l15) * 32 + quad * 8];
#pragma unroll
      for (int r = 0; r < 2; ++r)
#pragma unroll
        for (int c = 0; c < 2; ++c)
          acc[h][r][c] = __builtin_amdgcn_mfma_f32_16x16x32_bf16(fa[r], fb[c], acc[h][r][c], 0, 0, 0);
    }
  }

  // softmax over heads: purely per-lane (lane holds same (n,m) for all h)
  const float scale = 0.08838834764831845f;  // 1/sqrt(128)
#pragma unroll
  for (int r = 0; r < 2; ++r)
#pragma unroll
    for (int c = 0; c < 2; ++c)
#pragma unroll
      for (int i = 0; i < 4; ++i) {
        float mx = acc[0][r][c][i];
#pragma unroll
        for (int h = 1; h < 8; ++h) mx = fmaxf(mx, acc[h][r][c][i]);
        float sum = 0.f;
#pragma unroll
        for (int h = 0; h < 8; ++h) {
          float e = __expf((acc[h][r][c][i] - mx) * scale);
          acc[h][r][c][i] = e;
          sum += e;
        }
        float inv = 1.f / sum;
#pragma unroll
        for (int h = 0; h < 8; ++h) acc[h][r][c][i] *= inv;
      }

  // direct register -> global stores: m = l15 (lane-contiguous, 32B segments)
#pragma unroll
  for (int h = 0; h < 8; ++h) {
    u16* ph = P + (long)h * BS * BS;
#pragma unroll
    for (int r = 0; r < 2; ++r)
#pragma unroll
      for (int c = 0; c < 2; ++c)
#pragma unroll
        for (int i = 0; i < 4; ++i)
          ph[(long)(n0 + r * 16 + quad * 4 + i) * BS + m0 + wv * 32 + c * 16 + l15] =
              f32_bf16(acc[h][r][c][i]);
  }
}

// ---- residual + 4 bf16 partials + column-bias + layernorm; fp32 (+bf16) out ----
__global__ __launch_bounds__(256) void ln_residual_p4(
    const float* __restrict__ x,
    const u16* __restrict__ p0, const u16* __restrict__ p1,
    const u16* __restrict__ p2, const u16* __restrict__ p3,
    const float* __restrict__ colb, const float* __restrict__ g, const float* __restrict__ b,
    float* __restrict__ out32, u16* __restrict__ out16) {
  const int row = blockIdx.x, t = threadIdx.x;
  const long base = (long)row * EMB;
  float4 v = ((const float4*)(x + base))[t];
  ushort4 a0 = ((const ushort4*)(p0 + base))[t];
  ushort4 a1 = ((const ushort4*)(p1 + base))[t];
  ushort4 a2 = ((const ushort4*)(p2 + base))[t];
  ushort4 a3 = ((const ushort4*)(p3 + base))[t];
  float4 cb = ((const float4*)colb)[t];
  v.x += bf2f(a0.x) + bf2f(a1.x) + bf2f(a2.x) + bf2f(a3.x) + cb.x;
  v.y += bf2f(a0.y) + bf2f(a1.y) + bf2f(a2.y) + bf2f(a3.y) + cb.y;
  v.z += bf2f(a0.z) + bf2f(a1.z) + bf2f(a2.z) + bf2f(a3.z) + cb.z;
  v.w += bf2f(a0.w) + bf2f(a1.w) + bf2f(a2.w) + bf2f(a3.w) + cb.w;
  float s = v.x + v.y + v.z + v.w;
  float q = v.x * v.x + v.y * v.y + v.z * v.z + v.w * v.w;
#pragma unroll
  for (int off = 32; off > 0; off >>= 1) {
    s += __shfl_xor(s, off);
    q += __shfl_xor(q, off);
  }
  __shared__ float red[8];
  const int wv = t >> 6, lane = t & 63;
  if (lane == 0) { red[wv] = s; red[4 + wv] = q; }
  __syncthreads();
  s = red[0] + red[1] + red[2] + red[3];
  q = red[4] + red[5] + red[6] + red[7];
  const float mean = s * (1.f / EMB);
  const float var = q * (1.f / EMB) - mean * mean;
  const float rstd = rsqrtf(var + 1e-5f);
  float4 gg = ((const float4*)g)[t];
  float4 bb = ((const float4*)b)[t];
  float4 o;
  o.x = (v.x - mean) * rstd * gg.x + bb.x;
  o.y = (v.y - mean) * rstd * gg.y + bb.y;
  o.z = (v.z - mean) * rstd * gg.z + bb.z;
  o.w = (v.w - mean) * rstd * gg.w + bb.w;
  ((float4*)(out32 + base))[t] = o;
  if (out16) {
    ushort4 ho;
    ho.x = f32_bf16(o.x); ho.y = f32_bf16(o.y); ho.z = f32_bf16(o.z); ho.w = f32_bf16(o.w);
    ((ushort4*)(out16 + base))[t] = ho;
  }
}

extern "C" void kernel_launch(void* const* d_in, const int* in_sizes, int n_in,
                              void* d_out, int out_size, void* d_ws, size_t ws_size,
                              hipStream_t stream) {
  const float* x1 = (const float*)d_in[0];
  const float* x2 = (const float*)d_in[1];
  const float* Wq = (const float*)d_in[2];
  const float* bq = (const float*)d_in[3];
  const float* Wk = (const float*)d_in[4];
  const float* bk = (const float*)d_in[5];
  const float* Wv = (const float*)d_in[6];
  const float* bv = (const float*)d_in[7];
  const float* Wo = (const float*)d_in[8];
  const float* bo = (const float*)d_in[9];
  const float* W1 = (const float*)d_in[10];
  const float* b1 = (const float*)d_in[11];
  const float* W2 = (const float*)d_in[12];
  const float* b2 = (const float*)d_in[13];
  const float* g1 = (const float*)d_in[14];
  const float* be1 = (const float*)d_in[15];
  const float* g2 = (const float*)d_in[16];
  const float* be2 = (const float*)d_in[17];

  char* ws = (char*)d_ws;
  const size_t MB = 1ull << 20;
  // bf16 convert region (contiguous, 32 MB):
  u16* x1b = (u16*)(ws + 0 * MB);    // dead after qkv -> pv partial 0
  u16* x2b = (u16*)(ws + 4 * MB);    // dead after qkv -> pv partial 1
  u16* Wqb = (u16*)(ws + 8 * MB);
  u16* Wkb = (u16*)(ws + 10 * MB);
  u16* Wvb = (u16*)(ws + 12 * MB);
  u16* Wob = (u16*)(ws + 14 * MB);
  u16* W1b = (u16*)(ws + 16 * MB);
  u16* W2b = (u16*)(ws + 24 * MB);
  // attention buffers:
  u16* Qb  = (u16*)(ws + 32 * MB);   // dead after scores -> pv partial 2
  u16* Kb  = (u16*)(ws + 36 * MB);   // dead after scores -> pv partial 3
  u16* Vtb = (u16*)(ws + 40 * MB);   // 4 MB (transposed V: [h*128+d][m], ld 2048)
  u16* attnb = (u16*)(ws + 44 * MB); // 4 MB
  u16* P   = (u16*)(ws + 48 * MB);   // 64 MB (dead after pv_kernel)
  // post-attention region aliases P:
  u16* woP[4] = {(u16*)(ws + 48 * MB), (u16*)(ws + 52 * MB),
                 (u16*)(ws + 56 * MB), (u16*)(ws + 60 * MB)};   // 16 MB
  float* h32  = (float*)(ws + 64 * MB);  // 8 MB
  u16*  h16   = (u16*)(ws + 72 * MB);    // 4 MB
  u16*  ffn1b = (u16*)(ws + 76 * MB);    // 16 MB
  u16* f2P[4] = {(u16*)(ws + 92 * MB), (u16*)(ws + 96 * MB),
                 (u16*)(ws + 100 * MB), (u16*)(ws + 104 * MB)}; // 16 MB -> 108 peak

  // 1. all fp32->bf16 conversions
  CvtArgs ca;
  ca.src[0] = x1; ca.src[1] = x2; ca.src[2] = Wq; ca.src[3] = Wk;
  ca.src[4] = Wv; ca.src[5] = Wo; ca.src[6] = W1; ca.src[7] = W2;
  cvt_all<<<16384, 256, 0, stream>>>(ca, (u16*)ws);

  // 2. Q/K/V projections (one launch, 384 blocks)
  qkv_kernel<<<dim3(8, 16, 3), 256, 0, stream>>>(x1b, x2b, Wqb, Wkb, Wvb, bq, bk, bv, Qb, Kb, Vtb);

  // 3. scores + softmax over heads -> P[h][n][m]
  scores_softmax<<<dim3(16, 64), 256, 0, stream>>>(Qb, Kb, P);

  // 4. PV split-K x4 (512 blocks), bf16 partials into x1b/x2b/Qb/Kb (all dead)
  pv_kernel<<<dim3(1, 16, 32), 256, 0, stream>>>(P, Vtb, x1b, x2b, Qb, Kb);

  // 5. attnb = sum of 4 partials
  reduce4p_bf16<<<2048, 256, 0, stream>>>(x1b, x2b, Qb, Kb, attnb);

  // 6. Wo GEMM split-K x4 (512 blocks), bf16 partials (bias folded into LN)
  gemm_bt_k<<<dim3(8, 16, 4), 256, 0, stream>>>(attnb, Wob, woP[0], nullptr,
                                                256, 1024, 1024, 1024,
                                                256, 256, (long)BS * 1024, 1, 0);

  // 7. h = LN(x1 + sum(woP) + bo)
  ln_residual_p4<<<2048, 256, 0, stream>>>(x1, woP[0], woP[1], woP[2], woP[3],
                                           bo, g1, be1, h32, h16);

  // 8. FFN1 (+bias+relu), 512 blocks
  gemm_bt_k<<<dim3(32, 16, 1), 256, 0, stream>>>(h16, W1b, ffn1b, b1,
                                                 1024, 1024, 1024, 4096,
                                                 0, 0, 0, 1, 1);

  // 9. FFN2 split-K x4 (512 blocks), bf16 partials (bias folded into LN)
  gemm_bt_k<<<dim3(8, 16, 4), 256, 0, stream>>>(ffn1b, W2b, f2P[0], nullptr,
                                                1024, 4096, 4096, 1024,
                                                1024, 1024, (long)BS * 1024, 1, 0);

  // 10. out = LN(h + sum(f2P) + b2)
  ln_residual_p4<<<2048, 256, 0, stream>>>(h32, f2P[0], f2P[1], f2P[2], f2P[3],
                                           b2, g2, be2, (float*)d_out, nullptr);
}